// Round 26
// baseline (98.493 us; speedup 1.0000x reference)
//
#include <hip/hip_runtime.h>
#include <math.h>

#define T_LEN 6000
#define NROWS 4096          // B*C = 512*8
#define NCH 8
#define F_BINS 129
#define CF (NCH*F_BINS)     // 1032
#define NSLOT 16            // contention-splitting copies of the bary accumulator
#define REG_EPS 1e-7f

typedef _Float16 half8 __attribute__((ext_vector_type(8)));
typedef _Float16 half4_t __attribute__((ext_vector_type(4)));
typedef float f32x4 __attribute__((ext_vector_type(4)));

// ---------------- Kernel B: Welch PSD + row mean + barycenter accumulation ----------------
// r25 structure (4 waves x 4 N-tiles, bf[4][8] persistent, 2x A-read reuse) with the
// spill fixed: (256,1) instead of (256,2). r25's (256,2) let the allocator pick the
// 128-VGPR occupancy step and SPILL ~40 regs (WRITE_SIZE 4.5->8.6MB, FETCH +1.1MB)
// for 4-waves/SIMD occupancy the 512-block grid can't use (2 blocks/CU). (256,1)
// permits ~170-190 VGPR (2 waves/SIMD step) = same residency, zero spill.
#define PSD_ROWS 8
__global__ __launch_bounds__(256, 1) void psd_kernel(const float* __restrict__ x,
                                                     float* __restrict__ psd,
                                                     float* __restrict__ means,
                                                     float* __restrict__ ssumN) {
  int tid = threadIdx.x;
  int lane = tid & 63;
  int w = tid >> 6;          // 0..3
  int l15 = lane & 15, l4 = lane >> 4;
  __shared__ __align__(16) _Float16 xh[2][6272];
  __shared__ float rowm[3][4];
  __shared__ float psd_buf[PSD_ROWS][132];
  __shared__ float mean_buf[PSD_ROWS];

  // persistent B fragments: nt = w + 4*i, col n = 16*nt+l15, k = 32*kk+8*l4+e
  half8 bf[4][8];
  #pragma unroll
  for (int i = 0; i < 4; ++i) {
    int n = 16 * (w + 4 * i) + l15;
    int nn = (n < 129) ? n : (n - 128);
    for (int kk = 0; kk < 8; ++kk) {
      half8 hb;
      for (int e = 0; e < 8; ++e) {
        int k = 32 * kk + 8 * l4 + e;
        float ang = (float)((nn * k) & 255) * (6.283185307179586f / 256.f);
        float s, c;
        __sincosf(ang, &s, &c);
        hb[e] = (_Float16)((n < 129) ? c : s);
      }
      bf[i][kk] = hb;
    }
  }

  int r0 = blockIdx.x * PSD_ROWS;
  float* myslot = ssumN + (size_t)(blockIdx.x & (NSLOT - 1)) * CF;
  float4 v[7];
  // prologue: load + stage row 0 (rowm slot 0), then load row 1
  {
    const float* xr = x + (size_t)r0 * T_LEN;
    #pragma unroll
    for (int j = 0; j < 7; ++j) {
      int c = tid + 256 * j;
      v[j] = (c < 1500) ? ((const float4*)xr)[c] : make_float4(0.f, 0.f, 0.f, 0.f);
    }
    float rs = 0.f;
    #pragma unroll
    for (int j = 0; j < 7; ++j) {
      int c = tid + 256 * j;
      if (c < 1568) {
        float4 q = v[j];
        rs += q.x + q.y + q.z + q.w;
        half4_t h = { (_Float16)q.x, (_Float16)q.y, (_Float16)q.z, (_Float16)q.w };
        int byte = 8 * c;
        byte ^= ((byte >> 8) & 7) << 4;
        *(half4_t*)((char*)xh[0] + byte) = h;
      }
    }
    #pragma unroll
    for (int off = 32; off >= 1; off >>= 1) rs += __shfl_xor(rs, off);
    if (lane == 0) rowm[0][w] = rs;
    const float* x1 = x + (size_t)(r0 + 1) * T_LEN;
    #pragma unroll
    for (int j = 0; j < 7; ++j) {
      int c = tid + 256 * j;
      v[j] = (c < 1500) ? ((const float4*)x1)[c] : make_float4(0.f, 0.f, 0.f, 0.f);
    }
  }
  __syncthreads();                              // xh[0] visible

  for (int jr = 0; jr < PSD_ROWS; ++jr) {
    int r = r0 + jr;
    const char* xcur = (const char*)xh[jr & 1];
    // ---- phase 1: stage row jr+1 into other buffer; issue loads row jr+2 ----
    if (jr + 1 < PSD_ROWS) {
      char* xnxt = (char*)xh[(jr + 1) & 1];
      float rs = 0.f;
      #pragma unroll
      for (int j = 0; j < 7; ++j) {
        int c = tid + 256 * j;
        if (c < 1568) {
          float4 q = v[j];
          rs += q.x + q.y + q.z + q.w;
          half4_t h = { (_Float16)q.x, (_Float16)q.y, (_Float16)q.z, (_Float16)q.w };
          int byte = 8 * c;
          byte ^= ((byte >> 8) & 7) << 4;
          *(half4_t*)(xnxt + byte) = h;
        }
      }
      if (jr + 2 < PSD_ROWS) {
        const float* xn = x + (size_t)(r + 2) * T_LEN;
        #pragma unroll
        for (int j = 0; j < 7; ++j) {
          int c = tid + 256 * j;
          v[j] = (c < 1500) ? ((const float4*)xn)[c] : make_float4(0.f, 0.f, 0.f, 0.f);
        }
      }
      #pragma unroll
      for (int off = 32; off >= 1; off >>= 1) rs += __shfl_xor(rs, off);
      if (lane == 0) rowm[(jr + 1) % 3][w] = rs;
    }
    // ---- GEMM on xcur (A-frag read once, reused by 4 N-tiles) ----
    f32x4 acc[4][3];
    #pragma unroll
    for (int i = 0; i < 4; ++i)
      #pragma unroll
      for (int mt = 0; mt < 3; ++mt)
        acc[i][mt] = (f32x4){0.f, 0.f, 0.f, 0.f};
    #pragma unroll
    for (int kk = 0; kk < 8; ++kk) {
      half8 a[3];
      #pragma unroll
      for (int mt = 0; mt < 3; ++mt) {
        int ab = 4096 * mt + 256 * l15 + 64 * kk + 16 * l4;
        ab ^= ((ab >> 8) & 7) << 4;
        a[mt] = *(const half8*)(xcur + ab);
      }
      #pragma unroll
      for (int mt = 0; mt < 3; ++mt) {
        acc[0][mt] = __builtin_amdgcn_mfma_f32_16x16x32_f16(a[mt], bf[0][kk], acc[0][mt], 0, 0, 0);
        acc[1][mt] = __builtin_amdgcn_mfma_f32_16x16x32_f16(a[mt], bf[1][kk], acc[1][mt], 0, 0, 0);
        acc[2][mt] = __builtin_amdgcn_mfma_f32_16x16x32_f16(a[mt], bf[2][kk], acc[2][mt], 0, 0, 0);
        acc[3][mt] = __builtin_amdgcn_mfma_f32_16x16x32_f16(a[mt], bf[3][kk], acc[3][mt], 0, 0, 0);
      }
    }
    // per-lane column partials; C/D: row m = 16*mt+4*l4+j, col n = 16*nt+l15
    float s[4];
    #pragma unroll
    for (int i = 0; i < 4; ++i) {
      float t = 0.f;
      #pragma unroll
      for (int j = 0; j < 4; ++j) {
        t += acc[i][0][j] * acc[i][0][j];
        t += acc[i][1][j] * acc[i][1][j];
        if (4 * l4 + j < 13) t += acc[i][2][j] * acc[i][2][j];  // mask m>=45
      }
      t += __shfl_xor(t, 16);
      t += __shfl_xor(t, 32);
      s[i] = t;
    }
    // ---- register->LDS epilogue ----
    // i=0: cos bins 16w+l15 ; i=1: cos bins 64+16w+l15 ;
    // i=2: col 128+16w+l15 (sin pair of i=0; col 128 = Nyquist) ; i=3: sin pair of i=1.
    if (l4 == 0) {
      if (w == 0 && l15 == 0) {
        psd_buf[jr][0] = REG_EPS;                               // detrended DC
        psd_buf[jr][128] = s[2] * (1.f / 11520.f) + REG_EPS;    // Nyquist
        psd_buf[jr][64] = (s[1] + s[3]) * (1.f / 5760.f) + REG_EPS;
      } else {
        psd_buf[jr][16 * w + l15] = (s[0] + s[2]) * (1.f / 5760.f) + REG_EPS;
        psd_buf[jr][64 + 16 * w + l15] = (s[1] + s[3]) * (1.f / 5760.f) + REG_EPS;
      }
    }
    if (tid == 0) {
      float ms = rowm[jr % 3][0] + rowm[jr % 3][1] + rowm[jr % 3][2] + rowm[jr % 3][3];
      mean_buf[jr] = ms * (1.f / (float)T_LEN);
    }
    __syncthreads();                            // xh stage/read ordering
  }

  // ---- bulk global epilogue ----
  if (tid < F_BINS) {
    #pragma unroll
    for (int jr = 0; jr < PSD_ROWS; ++jr) {
      float p = psd_buf[jr][tid];
      psd[(size_t)(r0 + jr) * F_BINS + tid] = p;
      atomicAdd(&myslot[jr * F_BINS + tid], sqrtf(p) * (1.f / (float)F_BINS));
    }
  }
  if (tid < PSD_ROWS) means[r0 + tid] = mean_buf[tid];
}

// ---------------- Kernel E: conv with fused filter construction (r19-proven, unchanged) ----------------
#define BSTRIDE 296
__global__ __launch_bounds__(512) void conv_kernel(const float* __restrict__ x,
                                                   const float* __restrict__ means,
                                                   const float* __restrict__ psd,
                                                   const float* __restrict__ ssumN,
                                                   float* __restrict__ y) {
  int rc = blockIdx.x;
  int c = rc & (NCH - 1);
  int tid = threadIdx.x;
  int lane = tid & 63;
  int w = tid >> 6;          // 0..7
  __shared__ __align__(16) char smem[24576];
  _Float16* xh = (_Float16*)smem;                 // [0, 13056)
  _Float16* Bp = (_Float16*)(smem + 13056);       // [13056, 22528)
  float* part = (float*)(smem + 13056);           // overlays Bp until hv combined
  float* dv = (float*)(smem + 22528);             // [22528, 23044)
  float* hv = (float*)(smem + 23044);             // [23044, 23560)
  const float* xr = x + (size_t)rc * T_LEN;
  float mean = means[rc];
  if (tid < F_BINS) {
    float s = 0.f;
    #pragma unroll
    for (int p = 0; p < NSLOT; ++p)
      s += ssumN[(size_t)p * CF + c * F_BINS + tid];
    dv[tid] = s * rsqrtf(psd[(size_t)rc * F_BINS + tid]);
  }
  #pragma unroll
  for (int j = 0; j < 4; ++j) {
    int q = tid + 512 * j;
    if (q < 1632) {
      int cc = q - 32;
      half4_t h;
      if (cc >= 0 && cc < 1500) {
        float4 vv = ((const float4*)xr)[cc];
        h = (half4_t){ (_Float16)(vv.x - mean), (_Float16)(vv.y - mean),
                       (_Float16)(vv.z - mean), (_Float16)(vv.w - mean) };
      } else {
        h = (half4_t){ (_Float16)0.f, (_Float16)0.f, (_Float16)0.f, (_Float16)0.f };
      }
      *(half4_t*)((char*)xh + 8 * q) = h;
    }
  }
  __syncthreads();
  if (tid < 258) {
    int t = tid >> 1, p = tid & 1;
    int k0 = p ? 64 : 1;
    int nk = p ? 64 : 63;
    float stc, sts;
    __sincosf((float)t * (6.283185307179586f / 256.f), &sts, &stc);
    float cr, ci;
    __sincosf((float)((t * k0) & 255) * (6.283185307179586f / 256.f), &ci, &cr);
    float acc = 0.f;
    for (int q = 0; q < nk; ++q) {
      acc = fmaf(dv[k0 + q], cr, acc);
      float nr = cr * stc - ci * sts;
      ci = cr * sts + ci * stc;
      cr = nr;
    }
    part[tid] = acc;
  }
  __syncthreads();
  if (tid < F_BINS) {
    float val = dv[0] + ((tid & 1) ? -dv[128] : dv[128]) +
                2.f * (part[2 * tid] + part[2 * tid + 1]);
    hv[tid] = val * (1.f / 256.f);
  }
  __syncthreads();
  #pragma unroll
  for (int j = 0; j < 3; ++j) {
    int idx = tid + 512 * j;
    if (idx < 1152) {
      int n = idx & 15;
      int qq = idx >> 4;
      int s0 = 4 * qq - n - 1;
      half4_t h;
      #pragma unroll
      for (int e = 0; e < 4; ++e) {
        int s = s0 + e;
        float hvv = 0.f;
        if (s >= 0 && s < 256) {
          int ii = s - 127; if (ii < 0) ii = -ii;
          hvv = hv[ii];
        }
        h[e] = (_Float16)hvv;
      }
      *(half4_t*)((char*)Bp + (size_t)n * (2 * BSTRIDE) + 8 * qq) = h;
    }
  }
  __syncthreads();

  int l15 = lane & 15, l4 = lane >> 4;
  f32x4 acc0 = {0.f,0.f,0.f,0.f}, acc1 = {0.f,0.f,0.f,0.f}, acc2 = {0.f,0.f,0.f,0.f};
  const _Float16* bbase = &Bp[BSTRIDE * l15 + 8 * l4];
  const _Float16* abase = &xh[16 * l15 + 8 * l4 + 768 * w];
  #pragma unroll
  for (int kk = 0; kk < 9; ++kk) {
    half8 b = *(const half8*)(bbase + 32 * kk);
    half8 a0 = *(const half8*)(abase + 32 * kk);
    half8 a1 = *(const half8*)(abase + 256 + 32 * kk);
    half8 a2 = *(const half8*)(abase + 512 + 32 * kk);
    acc0 = __builtin_amdgcn_mfma_f32_16x16x32_f16(a0, b, acc0, 0, 0, 0);
    acc1 = __builtin_amdgcn_mfma_f32_16x16x32_f16(a1, b, acc1, 0, 0, 0);
    acc2 = __builtin_amdgcn_mfma_f32_16x16x32_f16(a2, b, acc2, 0, 0, 0);
  }
  __syncthreads();
  float* bw = (float*)smem + 768 * w;
  #pragma unroll
  for (int i = 0; i < 3; ++i) {
    f32x4 a = (i == 0) ? acc0 : (i == 1) ? acc1 : acc2;
    #pragma unroll
    for (int j = 0; j < 4; ++j)
      bw[256 * i + 64 * l4 + 16 * j + l15] = a[j];
  }
  float* yr = y + (size_t)rc * T_LEN + 768 * w;
  const float4* b4 = (const float4*)bw;
  #pragma unroll
  for (int cc = 0; cc < 3; ++cc) {
    int fi = 768 * w + 256 * cc + 4 * lane;
    if (fi < T_LEN)
      *(float4*)&yr[256 * cc + 4 * lane] = b4[64 * cc + lane];
  }
}

extern "C" void kernel_launch(void* const* d_in, const int* in_sizes, int n_in,
                              void* d_out, int out_size, void* d_ws, size_t ws_size,
                              hipStream_t stream) {
  const float* x = (const float*)d_in[0];
  float* out = (float*)d_out;
  float* psd   = (float*)d_ws;                         //   528,384 f
  float* ssumN = psd + (size_t)NROWS * F_BINS;         // 16*1,032 f
  float* means = ssumN + (size_t)NSLOT * CF;           //     4,096 f
  hipMemsetAsync(ssumN, 0, (size_t)NSLOT * CF * sizeof(float), stream);
  psd_kernel<<<NROWS / PSD_ROWS, 256, 0, stream>>>(x, psd, means, ssumN);
  conv_kernel<<<NROWS, 512, 0, stream>>>(x, means, psd, ssumN, out);
}

// Round 27
// 89.852 us; speedup vs baseline: 1.0962x; 1.0962x over previous
//
#include <hip/hip_runtime.h>
#include <math.h>

#define T_LEN 6000
#define NROWS 4096          // B*C = 512*8
#define NCH 8
#define F_BINS 129
#define CF (NCH*F_BINS)     // 1032
#define NSLOT 16            // contention-splitting copies of the bary accumulator
#define REG_EPS 1e-7f

typedef _Float16 half8 __attribute__((ext_vector_type(8)));
typedef _Float16 half4_t __attribute__((ext_vector_type(4)));
typedef float f32x4 __attribute__((ext_vector_type(4)));

// ---------------- Kernel B: Welch PSD + row mean + barycenter accumulation ----------------
// ROUND-25 EXACT RESTORE (90.6us total, best measured). 4 waves x 4 N-tiles
// (bf[4][8] persistent, 2x A-read reuse vs r23), double-buffered LDS pipeline,
// deferred global epilogue. (256,2): allocator picks the 128-VGPR step and spills
// ~4MB -- MEASURED CHEAPER than (256,1)'s honest 152-VGPR alloc, which halved
// occupancy to 1 wave/SIMD (r26: 98.5us vs 90.6). Both neighbors falsified; keep 128.
#define PSD_ROWS 8
__global__ __launch_bounds__(256, 2) void psd_kernel(const float* __restrict__ x,
                                                     float* __restrict__ psd,
                                                     float* __restrict__ means,
                                                     float* __restrict__ ssumN) {
  int tid = threadIdx.x;
  int lane = tid & 63;
  int w = tid >> 6;          // 0..3
  int l15 = lane & 15, l4 = lane >> 4;
  __shared__ __align__(16) _Float16 xh[2][6272];
  __shared__ float rowm[3][4];
  __shared__ float psd_buf[PSD_ROWS][132];
  __shared__ float mean_buf[PSD_ROWS];

  // persistent B fragments: nt = w + 4*i, col n = 16*nt+l15, k = 32*kk+8*l4+e
  half8 bf[4][8];
  #pragma unroll
  for (int i = 0; i < 4; ++i) {
    int n = 16 * (w + 4 * i) + l15;
    int nn = (n < 129) ? n : (n - 128);
    for (int kk = 0; kk < 8; ++kk) {
      half8 hb;
      for (int e = 0; e < 8; ++e) {
        int k = 32 * kk + 8 * l4 + e;
        float ang = (float)((nn * k) & 255) * (6.283185307179586f / 256.f);
        float s, c;
        __sincosf(ang, &s, &c);
        hb[e] = (_Float16)((n < 129) ? c : s);
      }
      bf[i][kk] = hb;
    }
  }

  int r0 = blockIdx.x * PSD_ROWS;
  float* myslot = ssumN + (size_t)(blockIdx.x & (NSLOT - 1)) * CF;
  float4 v[7];
  // prologue: load + stage row 0 (rowm slot 0), then load row 1
  {
    const float* xr = x + (size_t)r0 * T_LEN;
    #pragma unroll
    for (int j = 0; j < 7; ++j) {
      int c = tid + 256 * j;
      v[j] = (c < 1500) ? ((const float4*)xr)[c] : make_float4(0.f, 0.f, 0.f, 0.f);
    }
    float rs = 0.f;
    #pragma unroll
    for (int j = 0; j < 7; ++j) {
      int c = tid + 256 * j;
      if (c < 1568) {
        float4 q = v[j];
        rs += q.x + q.y + q.z + q.w;
        half4_t h = { (_Float16)q.x, (_Float16)q.y, (_Float16)q.z, (_Float16)q.w };
        int byte = 8 * c;
        byte ^= ((byte >> 8) & 7) << 4;
        *(half4_t*)((char*)xh[0] + byte) = h;
      }
    }
    #pragma unroll
    for (int off = 32; off >= 1; off >>= 1) rs += __shfl_xor(rs, off);
    if (lane == 0) rowm[0][w] = rs;
    const float* x1 = x + (size_t)(r0 + 1) * T_LEN;
    #pragma unroll
    for (int j = 0; j < 7; ++j) {
      int c = tid + 256 * j;
      v[j] = (c < 1500) ? ((const float4*)x1)[c] : make_float4(0.f, 0.f, 0.f, 0.f);
    }
  }
  __syncthreads();                              // xh[0] visible

  for (int jr = 0; jr < PSD_ROWS; ++jr) {
    int r = r0 + jr;
    const char* xcur = (const char*)xh[jr & 1];
    // ---- phase 1: stage row jr+1 into other buffer; issue loads row jr+2 ----
    if (jr + 1 < PSD_ROWS) {
      char* xnxt = (char*)xh[(jr + 1) & 1];
      float rs = 0.f;
      #pragma unroll
      for (int j = 0; j < 7; ++j) {
        int c = tid + 256 * j;
        if (c < 1568) {
          float4 q = v[j];
          rs += q.x + q.y + q.z + q.w;
          half4_t h = { (_Float16)q.x, (_Float16)q.y, (_Float16)q.z, (_Float16)q.w };
          int byte = 8 * c;
          byte ^= ((byte >> 8) & 7) << 4;
          *(half4_t*)(xnxt + byte) = h;
        }
      }
      if (jr + 2 < PSD_ROWS) {
        const float* xn = x + (size_t)(r + 2) * T_LEN;
        #pragma unroll
        for (int j = 0; j < 7; ++j) {
          int c = tid + 256 * j;
          v[j] = (c < 1500) ? ((const float4*)xn)[c] : make_float4(0.f, 0.f, 0.f, 0.f);
        }
      }
      #pragma unroll
      for (int off = 32; off >= 1; off >>= 1) rs += __shfl_xor(rs, off);
      if (lane == 0) rowm[(jr + 1) % 3][w] = rs;
    }
    // ---- GEMM on xcur (A-frag read once, reused by 4 N-tiles) ----
    f32x4 acc[4][3];
    #pragma unroll
    for (int i = 0; i < 4; ++i)
      #pragma unroll
      for (int mt = 0; mt < 3; ++mt)
        acc[i][mt] = (f32x4){0.f, 0.f, 0.f, 0.f};
    #pragma unroll
    for (int kk = 0; kk < 8; ++kk) {
      half8 a[3];
      #pragma unroll
      for (int mt = 0; mt < 3; ++mt) {
        int ab = 4096 * mt + 256 * l15 + 64 * kk + 16 * l4;
        ab ^= ((ab >> 8) & 7) << 4;
        a[mt] = *(const half8*)(xcur + ab);
      }
      #pragma unroll
      for (int mt = 0; mt < 3; ++mt) {
        acc[0][mt] = __builtin_amdgcn_mfma_f32_16x16x32_f16(a[mt], bf[0][kk], acc[0][mt], 0, 0, 0);
        acc[1][mt] = __builtin_amdgcn_mfma_f32_16x16x32_f16(a[mt], bf[1][kk], acc[1][mt], 0, 0, 0);
        acc[2][mt] = __builtin_amdgcn_mfma_f32_16x16x32_f16(a[mt], bf[2][kk], acc[2][mt], 0, 0, 0);
        acc[3][mt] = __builtin_amdgcn_mfma_f32_16x16x32_f16(a[mt], bf[3][kk], acc[3][mt], 0, 0, 0);
      }
    }
    // per-lane column partials; C/D: row m = 16*mt+4*l4+j, col n = 16*nt+l15
    float s[4];
    #pragma unroll
    for (int i = 0; i < 4; ++i) {
      float t = 0.f;
      #pragma unroll
      for (int j = 0; j < 4; ++j) {
        t += acc[i][0][j] * acc[i][0][j];
        t += acc[i][1][j] * acc[i][1][j];
        if (4 * l4 + j < 13) t += acc[i][2][j] * acc[i][2][j];  // mask m>=45
      }
      t += __shfl_xor(t, 16);
      t += __shfl_xor(t, 32);
      s[i] = t;
    }
    // ---- register->LDS epilogue ----
    // i=0: cos bins 16w+l15 ; i=1: cos bins 64+16w+l15 ;
    // i=2: col 128+16w+l15 (sin pair of i=0; col 128 = Nyquist) ; i=3: sin pair of i=1.
    if (l4 == 0) {
      if (w == 0 && l15 == 0) {
        psd_buf[jr][0] = REG_EPS;                               // detrended DC
        psd_buf[jr][128] = s[2] * (1.f / 11520.f) + REG_EPS;    // Nyquist
        psd_buf[jr][64] = (s[1] + s[3]) * (1.f / 5760.f) + REG_EPS;
      } else {
        psd_buf[jr][16 * w + l15] = (s[0] + s[2]) * (1.f / 5760.f) + REG_EPS;
        psd_buf[jr][64 + 16 * w + l15] = (s[1] + s[3]) * (1.f / 5760.f) + REG_EPS;
      }
    }
    if (tid == 0) {
      float ms = rowm[jr % 3][0] + rowm[jr % 3][1] + rowm[jr % 3][2] + rowm[jr % 3][3];
      mean_buf[jr] = ms * (1.f / (float)T_LEN);
    }
    __syncthreads();                            // xh stage/read ordering
  }

  // ---- bulk global epilogue ----
  if (tid < F_BINS) {
    #pragma unroll
    for (int jr = 0; jr < PSD_ROWS; ++jr) {
      float p = psd_buf[jr][tid];
      psd[(size_t)(r0 + jr) * F_BINS + tid] = p;
      atomicAdd(&myslot[jr * F_BINS + tid], sqrtf(p) * (1.f / (float)F_BINS));
    }
  }
  if (tid < PSD_ROWS) means[r0 + tid] = mean_buf[tid];
}

// ---------------- Kernel E: conv with fused filter construction (r19-proven, unchanged) ----------------
#define BSTRIDE 296
__global__ __launch_bounds__(512) void conv_kernel(const float* __restrict__ x,
                                                   const float* __restrict__ means,
                                                   const float* __restrict__ psd,
                                                   const float* __restrict__ ssumN,
                                                   float* __restrict__ y) {
  int rc = blockIdx.x;
  int c = rc & (NCH - 1);
  int tid = threadIdx.x;
  int lane = tid & 63;
  int w = tid >> 6;          // 0..7
  __shared__ __align__(16) char smem[24576];
  _Float16* xh = (_Float16*)smem;                 // [0, 13056)
  _Float16* Bp = (_Float16*)(smem + 13056);       // [13056, 22528)
  float* part = (float*)(smem + 13056);           // overlays Bp until hv combined
  float* dv = (float*)(smem + 22528);             // [22528, 23044)
  float* hv = (float*)(smem + 23044);             // [23044, 23560)
  const float* xr = x + (size_t)rc * T_LEN;
  float mean = means[rc];
  if (tid < F_BINS) {
    float s = 0.f;
    #pragma unroll
    for (int p = 0; p < NSLOT; ++p)
      s += ssumN[(size_t)p * CF + c * F_BINS + tid];
    dv[tid] = s * rsqrtf(psd[(size_t)rc * F_BINS + tid]);
  }
  #pragma unroll
  for (int j = 0; j < 4; ++j) {
    int q = tid + 512 * j;
    if (q < 1632) {
      int cc = q - 32;
      half4_t h;
      if (cc >= 0 && cc < 1500) {
        float4 vv = ((const float4*)xr)[cc];
        h = (half4_t){ (_Float16)(vv.x - mean), (_Float16)(vv.y - mean),
                       (_Float16)(vv.z - mean), (_Float16)(vv.w - mean) };
      } else {
        h = (half4_t){ (_Float16)0.f, (_Float16)0.f, (_Float16)0.f, (_Float16)0.f };
      }
      *(half4_t*)((char*)xh + 8 * q) = h;
    }
  }
  __syncthreads();
  if (tid < 258) {
    int t = tid >> 1, p = tid & 1;
    int k0 = p ? 64 : 1;
    int nk = p ? 64 : 63;
    float stc, sts;
    __sincosf((float)t * (6.283185307179586f / 256.f), &sts, &stc);
    float cr, ci;
    __sincosf((float)((t * k0) & 255) * (6.283185307179586f / 256.f), &ci, &cr);
    float acc = 0.f;
    for (int q = 0; q < nk; ++q) {
      acc = fmaf(dv[k0 + q], cr, acc);
      float nr = cr * stc - ci * sts;
      ci = cr * sts + ci * stc;
      cr = nr;
    }
    part[tid] = acc;
  }
  __syncthreads();
  if (tid < F_BINS) {
    float val = dv[0] + ((tid & 1) ? -dv[128] : dv[128]) +
                2.f * (part[2 * tid] + part[2 * tid + 1]);
    hv[tid] = val * (1.f / 256.f);
  }
  __syncthreads();
  #pragma unroll
  for (int j = 0; j < 3; ++j) {
    int idx = tid + 512 * j;
    if (idx < 1152) {
      int n = idx & 15;
      int qq = idx >> 4;
      int s0 = 4 * qq - n - 1;
      half4_t h;
      #pragma unroll
      for (int e = 0; e < 4; ++e) {
        int s = s0 + e;
        float hvv = 0.f;
        if (s >= 0 && s < 256) {
          int ii = s - 127; if (ii < 0) ii = -ii;
          hvv = hv[ii];
        }
        h[e] = (_Float16)hvv;
      }
      *(half4_t*)((char*)Bp + (size_t)n * (2 * BSTRIDE) + 8 * qq) = h;
    }
  }
  __syncthreads();

  int l15 = lane & 15, l4 = lane >> 4;
  f32x4 acc0 = {0.f,0.f,0.f,0.f}, acc1 = {0.f,0.f,0.f,0.f}, acc2 = {0.f,0.f,0.f,0.f};
  const _Float16* bbase = &Bp[BSTRIDE * l15 + 8 * l4];
  const _Float16* abase = &xh[16 * l15 + 8 * l4 + 768 * w];
  #pragma unroll
  for (int kk = 0; kk < 9; ++kk) {
    half8 b = *(const half8*)(bbase + 32 * kk);
    half8 a0 = *(const half8*)(abase + 32 * kk);
    half8 a1 = *(const half8*)(abase + 256 + 32 * kk);
    half8 a2 = *(const half8*)(abase + 512 + 32 * kk);
    acc0 = __builtin_amdgcn_mfma_f32_16x16x32_f16(a0, b, acc0, 0, 0, 0);
    acc1 = __builtin_amdgcn_mfma_f32_16x16x32_f16(a1, b, acc1, 0, 0, 0);
    acc2 = __builtin_amdgcn_mfma_f32_16x16x32_f16(a2, b, acc2, 0, 0, 0);
  }
  __syncthreads();
  float* bw = (float*)smem + 768 * w;
  #pragma unroll
  for (int i = 0; i < 3; ++i) {
    f32x4 a = (i == 0) ? acc0 : (i == 1) ? acc1 : acc2;
    #pragma unroll
    for (int j = 0; j < 4; ++j)
      bw[256 * i + 64 * l4 + 16 * j + l15] = a[j];
  }
  float* yr = y + (size_t)rc * T_LEN + 768 * w;
  const float4* b4 = (const float4*)bw;
  #pragma unroll
  for (int cc = 0; cc < 3; ++cc) {
    int fi = 768 * w + 256 * cc + 4 * lane;
    if (fi < T_LEN)
      *(float4*)&yr[256 * cc + 4 * lane] = b4[64 * cc + lane];
  }
}

extern "C" void kernel_launch(void* const* d_in, const int* in_sizes, int n_in,
                              void* d_out, int out_size, void* d_ws, size_t ws_size,
                              hipStream_t stream) {
  const float* x = (const float*)d_in[0];
  float* out = (float*)d_out;
  float* psd   = (float*)d_ws;                         //   528,384 f
  float* ssumN = psd + (size_t)NROWS * F_BINS;         // 16*1,032 f
  float* means = ssumN + (size_t)NSLOT * CF;           //     4,096 f
  hipMemsetAsync(ssumN, 0, (size_t)NSLOT * CF * sizeof(float), stream);
  psd_kernel<<<NROWS / PSD_ROWS, 256, 0, stream>>>(x, psd, means, ssumN);
  conv_kernel<<<NROWS, 512, 0, stream>>>(x, means, psd, ssumN, out);
}